// Round 1
// baseline (173.255 us; speedup 1.0000x reference)
//
#include <hip/hip_runtime.h>
#include <hip/hip_bf16.h>

#define F 128
// CAP=32 u16 entries => each node's bucket is exactly ONE 64B cache line.
// E[deg]=12, P(deg>=32)~1.2e-6; overflow list keeps full correctness anyway.
// NOTE: u16 src indices require n <= 65535 (n=50000 here).
#define CAP 32
#define NF 1024  // fill blocks in K1 (multiple of 8: 128 scan-groups x 8 col-classes)

typedef __bf16 bf16x8 __attribute__((ext_vector_type(8)));
typedef float f32x4 __attribute__((ext_vector_type(4)));

static __device__ __forceinline__ unsigned int f2bfbits(float f) {
  unsigned int u = __float_as_uint(f);
  return (u + 0x7fffu + ((u >> 16) & 1u)) >> 16;
}

// ---- K0: lstm (blocks 0..31) || zero deg+ovf_cnt (blocks 32..) -----------
__global__ __launch_bounds__(256) void lstm_zero_kernel(
    const float* __restrict__ W0, const float* __restrict__ w_ih,
    const float* __restrict__ b_ih, const float* __restrict__ b_hh,
    unsigned short* __restrict__ Wt, int* __restrict__ deg,
    int* __restrict__ ovf_cnt, int n) {
  __shared__ __align__(16) float srow[4][F];  // 2 KB
  __shared__ float sg[4][4 * F];              // 8 KB
  int b = blockIdx.x, t = threadIdx.x;
  if (b < 32) {
    int r0 = b * 4;
    for (int i = t; i < 4 * F; i += 256)
      srow[i >> 7][i & 127] = W0[(size_t)(r0 + (i >> 7)) * F + (i & 127)];
    __syncthreads();
#pragma unroll
    for (int half = 0; half < 2; half++) {
      int gc = t + half * 256;  // gate col 0..511
      float acc[4] = {0.f, 0.f, 0.f, 0.f};
      const float4* wv4 = (const float4*)(w_ih + (size_t)gc * F);
#pragma unroll 4
      for (int k4 = 0; k4 < F / 4; k4++) {
        float4 w = wv4[k4];
#pragma unroll
        for (int i = 0; i < 4; i++) {
          float4 s = *(const float4*)&srow[i][k4 * 4];
          acc[i] = fmaf(s.x, w.x, fmaf(s.y, w.y, fmaf(s.z, w.z, fmaf(s.w, w.w, acc[i]))));
        }
      }
      float bias = b_ih[gc] + b_hh[gc];
#pragma unroll
      for (int i = 0; i < 4; i++) sg[i][gc] = acc[i] + bias;
    }
    __syncthreads();
#pragma unroll
    for (int half = 0; half < 2; half++) {
      int idx2 = t + half * 256;  // 0..511 = 4 rows x 128 cols
      int rr = idx2 >> 7, c = idx2 & 127;
      float gi = sg[rr][c], gg = sg[rr][c + 2 * F], go = sg[rr][c + 3 * F];
      float si = 1.f / (1.f + expf(-gi));
      float so = 1.f / (1.f + expf(-go));
      float cc2 = si * tanhf(gg);
      // Wt[n][k] = bf16(W[k][n]), k = r0+rr, n = c
      Wt[(size_t)c * F + r0 + rr] = (unsigned short)f2bfbits(so * tanhf(cc2));
    }
  } else {
    int stride = ((int)gridDim.x - 32) * 256;
    for (int i = (b - 32) * 256 + t; i < n; i += stride) deg[i] = 0;
    if (b == 32 && t == 0) *ovf_cnt = 0;
  }
}

// ---- K1: XCD-local bucket fill (blocks < NF) || xw MFMA (blocks >= NF) ----
// Fill scan vectorized: int4 col loads => 4.6 iterations/thread (was 18.3),
// 4 independent match/atomic/store chains per iteration overlap in the
// memory system (latency-bound fix, not BW).
__global__ __launch_bounds__(256) void fill_xw_kernel(
    const int* __restrict__ row, const int* __restrict__ col,
    int* __restrict__ deg, unsigned short* __restrict__ bucket,
    int* __restrict__ ovf_cnt, int* __restrict__ ovf,
    const float* __restrict__ x, const unsigned short* __restrict__ Wt,
    unsigned short* __restrict__ xwb, int n, int e) {
  int b = blockIdx.x, t = threadIdx.x;
  if (b < NF) {
    int g = b & 7;                     // class == XCD (b%8) -> L2-local atomics
    int cg = b >> 3;                   // 0..NF/8-1 scan-group within class
    const int stride4 = (NF / 8) * 256;  // in int4 units
    const int e4 = e >> 2;
    const int4* col4 = (const int4*)col;
    for (int i4 = cg * 256 + t; i4 < e4; i4 += stride4) {
      int4 cv = col4[i4];
      int base = i4 * 4;
      int cs[4] = {cv.x, cv.y, cv.z, cv.w};
#pragma unroll
      for (int j = 0; j < 4; j++) {
        int c = cs[j];
        if ((c & 7) == g) {
          int r = row[base + j];
          int p = atomicAdd(&deg[c], 1);
          if (p < CAP) {
            bucket[(size_t)c * CAP + p] = (unsigned short)r;
          } else {
            int q = atomicAdd(ovf_cnt, 1);
            ovf[2 * q + 0] = c;
            ovf[2 * q + 1] = r;
          }
        }
      }
    }
    // tail e%4 (empty for e=600000): block 0 handles all classes
    if (b == 0 && t < (e & 3)) {
      int i = (e & ~3) + t;
      int c = col[i];
      int r = row[i];
      int p = atomicAdd(&deg[c], 1);
      if (p < CAP) {
        bucket[(size_t)c * CAP + p] = (unsigned short)r;
      } else {
        int q = atomicAdd(ovf_cnt, 1);
        ovf[2 * q + 0] = c;
        ovf[2 * q + 1] = r;
      }
    }
  } else {
    int w = t >> 6, l = t & 63;
    int q = l >> 4, m = l & 15;
    int m0 = (b - NF) * 64 + w * 16;
    int arow = m0 + m;
    bf16x8 a[4];
    const float4* xr4 = (const float4*)(x + (size_t)arow * F);
    bool rv = arow < n;
#pragma unroll
    for (int kc = 0; kc < 4; kc++) {
      uint4 pk = make_uint4(0u, 0u, 0u, 0u);
      if (rv) {
        float4 v0 = xr4[kc * 8 + q * 2 + 0];
        float4 v1 = xr4[kc * 8 + q * 2 + 1];
        pk.x = f2bfbits(v0.x) | (f2bfbits(v0.y) << 16);
        pk.y = f2bfbits(v0.z) | (f2bfbits(v0.w) << 16);
        pk.z = f2bfbits(v1.x) | (f2bfbits(v1.y) << 16);
        pk.w = f2bfbits(v1.z) | (f2bfbits(v1.w) << 16);
      }
      a[kc] = __builtin_bit_cast(bf16x8, pk);
    }
#pragma unroll
    for (int nc = 0; nc < 8; nc++) {
      f32x4 acc = {0.f, 0.f, 0.f, 0.f};
#pragma unroll
      for (int kc = 0; kc < 4; kc++) {
        uint4 bu = *(const uint4*)(Wt + (size_t)(nc * 16 + m) * F + kc * 32 + q * 8);
        acc = __builtin_amdgcn_mfma_f32_16x16x32_bf16(
            a[kc], __builtin_bit_cast(bf16x8, bu), acc, 0, 0, 0);
      }
#pragma unroll
      for (int r = 0; r < 4; r++) {
        int gr = m0 + q * 4 + r;
        if (gr < n)
          xwb[(size_t)gr * F + nc * 16 + m] = (unsigned short)f2bfbits(acc[r]);
      }
    }
  }
}

// ---- K2: pull aggregation + bias + relu + classifier (bf16 gather) --------
// Bucket line (64B) loaded as uint4 pairs (2 loads instead of 16 uniform
// ushort loads) -> gather addresses available after 1 memory round-trip.
// Two 16-wide CLAMPED+PREDICATED blocks cover all deg<=CAP; no 8-wide loop.
__global__ __launch_bounds__(256) void agg_kernel(
    const int* __restrict__ deg, const unsigned short* __restrict__ bucket,
    const unsigned int* __restrict__ xwb, const int* __restrict__ ovf_cnt,
    const int* __restrict__ ovf, const float* __restrict__ gcn_bias,
    const float* __restrict__ Wc, const float* __restrict__ bc,
    float* __restrict__ out, int n) {
  int wave = threadIdx.x >> 6;
  int lane = threadIdx.x & 63;
  int v = blockIdx.x * 4 + wave;
  if (v >= n) return;
  int d = deg[v];
  float dv = rsqrtf((float)(d + 1));  // +1 self loop, always > 0
  float ax, ay;
  {
    unsigned int u = xwb[(size_t)v * 64 + lane];  // self loop
    float sl = dv * dv;
    ax = sl * __uint_as_float(u << 16);
    ay = sl * __uint_as_float(u & 0xffff0000u);
  }
  int eend = d < CAP ? d : CAP;
  const unsigned short* bkt = bucket + (size_t)v * CAP;
  if (eend > 0) {
    // slots 0..15 (covers ~90% of nodes fully)
    uint4 b0 = *(const uint4*)(bkt);
    uint4 b1 = *(const uint4*)(bkt + 8);
    unsigned int wv[8] = {b0.x, b0.y, b0.z, b0.w, b1.x, b1.y, b1.z, b1.w};
    int s[16];
    float nr[16];
    unsigned int u[16];
#pragma unroll
    for (int q = 0; q < 16; q++) {
      int raw = (q & 1) ? (int)(wv[q >> 1] >> 16) : (int)(wv[q >> 1] & 0xffffu);
      s[q] = (q < eend) ? raw : 0;  // clamp padded slots to valid node 0
    }
#pragma unroll
    for (int q = 0; q < 16; q++) u[q] = xwb[(size_t)s[q] * 64 + lane];
#pragma unroll
    for (int q = 0; q < 16; q++) {
      float msk = (q < eend) ? 1.f : 0.f;
      nr[q] = rsqrtf((float)(deg[s[q]] + 1)) * dv * msk;
    }
#pragma unroll
    for (int q = 0; q < 16; q++) {
      ax = fmaf(nr[q], __uint_as_float(u[q] << 16), ax);
      ay = fmaf(nr[q], __uint_as_float(u[q] & 0xffff0000u), ay);
    }
    if (eend > 16) {  // slots 16..31 (P ~ 10%)
      uint4 b2 = *(const uint4*)(bkt + 16);
      uint4 b3 = *(const uint4*)(bkt + 24);
      unsigned int wv2[8] = {b2.x, b2.y, b2.z, b2.w, b3.x, b3.y, b3.z, b3.w};
#pragma unroll
      for (int q = 0; q < 16; q++) {
        int raw = (q & 1) ? (int)(wv2[q >> 1] >> 16) : (int)(wv2[q >> 1] & 0xffffu);
        s[q] = (q + 16 < eend) ? raw : 0;
      }
#pragma unroll
      for (int q = 0; q < 16; q++) u[q] = xwb[(size_t)s[q] * 64 + lane];
#pragma unroll
      for (int q = 0; q < 16; q++) {
        float msk = (q + 16 < eend) ? 1.f : 0.f;
        nr[q] = rsqrtf((float)(deg[s[q]] + 1)) * dv * msk;
      }
#pragma unroll
      for (int q = 0; q < 16; q++) {
        ax = fmaf(nr[q], __uint_as_float(u[q] << 16), ax);
        ay = fmaf(nr[q], __uint_as_float(u[q] & 0xffff0000u), ay);
      }
    }
  }
  if (d > CAP) {  // correctness fallback; statistically never taken
    int oc = *ovf_cnt;
    for (int k = 0; k < oc; k++) {
      if (ovf[2 * k] == v) {
        int s2 = ovf[2 * k + 1];
        float nrr = rsqrtf((float)(deg[s2] + 1)) * dv;
        unsigned int uu = xwb[(size_t)s2 * 64 + lane];
        ax = fmaf(nrr, __uint_as_float(uu << 16), ax);
        ay = fmaf(nrr, __uint_as_float(uu & 0xffff0000u), ay);
      }
    }
  }
  int f0 = lane * 2;
  float h0 = fmaxf(ax + gcn_bias[f0], 0.f);
  float h1 = fmaxf(ay + gcn_bias[f0 + 1], 0.f);
  float a0 = h0 * Wc[f0] + h1 * Wc[f0 + 1];
  float a1 = h0 * Wc[F + f0] + h1 * Wc[F + f0 + 1];
#pragma unroll
  for (int off = 32; off > 0; off >>= 1) {
    a0 += __shfl_down(a0, off);
    a1 += __shfl_down(a1, off);
  }
  if (lane == 0) {
    out[(size_t)v * 2 + 0] = a0 + bc[0];
    out[(size_t)v * 2 + 1] = a1 + bc[1];
  }
}

extern "C" void kernel_launch(void* const* d_in, const int* in_sizes, int n_in,
                              void* d_out, int out_size, void* d_ws, size_t ws_size,
                              hipStream_t stream) {
  const float* x        = (const float*)d_in[0];
  const float* W0       = (const float*)d_in[1];
  const float* w_ih     = (const float*)d_in[2];
  // d_in[3] = w_hh unused (h0 = 0)
  const float* b_ih     = (const float*)d_in[4];
  const float* b_hh     = (const float*)d_in[5];
  const float* gcn_bias = (const float*)d_in[6];
  const float* Wc       = (const float*)d_in[7];
  const float* bc       = (const float*)d_in[8];
  const int*   ei       = (const int*)d_in[9];

  const int n = in_sizes[0] / F;   // 50000
  const int e = in_sizes[9] / 2;   // 600000
  const int* row = ei;
  const int* col = ei + e;

  // workspace layout (256 B aligned chunks)
  char* wsb = (char*)d_ws;
  unsigned short* Wt = (unsigned short*)wsb;  wsb += 32768;  // bf16 W^T
  size_t n4 = ((size_t)n * 4 + 255) & ~(size_t)255;
  int*   deg     = (int*)wsb;                 wsb += n4;     // deg[n] + ovf_cnt
  int*   ovf_cnt = deg + n;                                  // zeroed in K0
  int*   ovf     = (int*)wsb;                 wsb += 8192;   // overflow pairs
  unsigned short* bucket = (unsigned short*)wsb;
  wsb += (size_t)n * CAP * 2;                                // 3.2 MB, 64B/node
  unsigned short* xwb = (unsigned short*)wsb;                // n*128 bf16

  const int NT = (n + 63) / 64;  // 782 xw tiles

  // K0: lstm (32 blocks) || zero deg+ovf_cnt (128 blocks)
  lstm_zero_kernel<<<32 + 128, 256, 0, stream>>>(W0, w_ih, b_ih, b_hh, Wt,
                                                 deg, ovf_cnt, n);

  // K1: XCD-local single-pass bucket fill (NF blocks) || xw = x@W MFMA (NT)
  fill_xw_kernel<<<NF + NT, 256, 0, stream>>>(row, col, deg, bucket, ovf_cnt,
                                              ovf, x, Wt, xwb, n, e);

  // K2: fused pull-aggregation + bias + relu + classifier (on-the-fly rsqrt)
  agg_kernel<<<(n + 3) / 4, 256, 0, stream>>>(deg, bucket,
                                              (const unsigned int*)xwb,
                                              ovf_cnt, ovf, gcn_bias, Wc, bc,
                                              (float*)d_out, n);
}

// Round 2
// 157.856 us; speedup vs baseline: 1.0976x; 1.0976x over previous
//
#include <hip/hip_runtime.h>
#include <hip/hip_bf16.h>
#include <hip/hip_fp16.h>

#define F 128
// CAP=32 u16 entries => each node's bucket is exactly ONE 64B cache line.
// E[deg]=12, P(deg>=32)~1.2e-6; overflow list keeps full correctness anyway.
// NOTE: u16 src indices require n <= 65535 (n=50000 here).
#define CAP 32
#define NF 1024  // fill blocks in K1 (128 scan-groups x 8 col-classes)
#define OVF_MAX 1024

typedef __bf16 bf16x8 __attribute__((ext_vector_type(8)));
typedef float f32x4 __attribute__((ext_vector_type(4)));

static __device__ __forceinline__ unsigned int f2bfbits(float f) {
  unsigned int u = __float_as_uint(f);
  return (u + 0x7fffu + ((u >> 16) & 1u)) >> 16;
}

// deg is PADDED: one int counter per 64B cache line (index v*16).
// Rationale: device-scope atomics execute at the memory-side LLC; packed
// counters put ~192 atomics from 8 XCDs on one line -> serialization.

// ---- K0: lstm (blocks 0..31) || zero deg+ovf_cnt (blocks 32..) -----------
__global__ __launch_bounds__(256) void lstm_zero_kernel(
    const float* __restrict__ W0, const float* __restrict__ w_ih,
    const float* __restrict__ b_ih, const float* __restrict__ b_hh,
    unsigned short* __restrict__ Wt, int* __restrict__ deg,
    int* __restrict__ ovf_cnt, int n) {
  __shared__ __align__(16) float srow[4][F];  // 2 KB
  __shared__ float sg[4][4 * F];              // 8 KB
  int b = blockIdx.x, t = threadIdx.x;
  if (b < 32) {
    int r0 = b * 4;
    for (int i = t; i < 4 * F; i += 256)
      srow[i >> 7][i & 127] = W0[(size_t)(r0 + (i >> 7)) * F + (i & 127)];
    __syncthreads();
#pragma unroll
    for (int half = 0; half < 2; half++) {
      int gc = t + half * 256;  // gate col 0..511
      float acc[4] = {0.f, 0.f, 0.f, 0.f};
      const float4* wv4 = (const float4*)(w_ih + (size_t)gc * F);
#pragma unroll 4
      for (int k4 = 0; k4 < F / 4; k4++) {
        float4 w = wv4[k4];
#pragma unroll
        for (int i = 0; i < 4; i++) {
          float4 s = *(const float4*)&srow[i][k4 * 4];
          acc[i] = fmaf(s.x, w.x, fmaf(s.y, w.y, fmaf(s.z, w.z, fmaf(s.w, w.w, acc[i]))));
        }
      }
      float bias = b_ih[gc] + b_hh[gc];
#pragma unroll
      for (int i = 0; i < 4; i++) sg[i][gc] = acc[i] + bias;
    }
    __syncthreads();
#pragma unroll
    for (int half = 0; half < 2; half++) {
      int idx2 = t + half * 256;  // 0..511 = 4 rows x 128 cols
      int rr = idx2 >> 7, c = idx2 & 127;
      float gi = sg[rr][c], gg = sg[rr][c + 2 * F], go = sg[rr][c + 3 * F];
      float si = 1.f / (1.f + expf(-gi));
      float so = 1.f / (1.f + expf(-go));
      float cc2 = si * tanhf(gg);
      // Wt[n][k] = bf16(W[k][n]), k = r0+rr, n = c
      Wt[(size_t)c * F + r0 + rr] = (unsigned short)f2bfbits(so * tanhf(cc2));
    }
  } else {
    // zero padded deg: n*16 ints = n*4 int4s
    int stride = ((int)gridDim.x - 32) * 256;
    int4* dz = (int4*)deg;
    int total4 = n * 4;
    const int4 z = make_int4(0, 0, 0, 0);
    for (int i = (b - 32) * 256 + t; i < total4; i += stride) dz[i] = z;
    if (b == 32 && t == 0) *ovf_cnt = 0;
  }
}

// ---- K1: XCD-local bucket fill (blocks < NF) || xw MFMA (blocks >= NF) ----
__global__ __launch_bounds__(256) void fill_xw_kernel(
    const int* __restrict__ row, const int* __restrict__ col,
    int* __restrict__ deg, unsigned short* __restrict__ bucket,
    int* __restrict__ ovf_cnt, int* __restrict__ ovf,
    const float* __restrict__ x, const unsigned short* __restrict__ Wt,
    unsigned short* __restrict__ xwb, int n, int e) {
  int b = blockIdx.x, t = threadIdx.x;
  if (b < NF) {
    int g = b & 7;    // class == XCD (b%8)
    int cg = b >> 3;  // 0..NF/8-1 scan-group within class
    const int stride = (NF / 8) * 256;
    for (int i = cg * 256 + t; i < e; i += stride) {
      int c = col[i];
      if ((c & 7) == g) {
        int r = row[i];
        int p = atomicAdd(&deg[(size_t)c * 16], 1);  // line-exclusive counter
        if (p < CAP) {
          bucket[(size_t)c * CAP + p] = (unsigned short)r;
        } else {
          int q = atomicAdd(ovf_cnt, 1);
          if (q < OVF_MAX) {
            ovf[2 * q + 0] = c;
            ovf[2 * q + 1] = r;
          }
        }
      }
    }
  } else {
    int w = t >> 6, l = t & 63;
    int q = l >> 4, m = l & 15;
    int m0 = (b - NF) * 64 + w * 16;
    int arow = m0 + m;
    bf16x8 a[4];
    const float4* xr4 = (const float4*)(x + (size_t)arow * F);
    bool rv = arow < n;
#pragma unroll
    for (int kc = 0; kc < 4; kc++) {
      uint4 pk = make_uint4(0u, 0u, 0u, 0u);
      if (rv) {
        float4 v0 = xr4[kc * 8 + q * 2 + 0];
        float4 v1 = xr4[kc * 8 + q * 2 + 1];
        pk.x = f2bfbits(v0.x) | (f2bfbits(v0.y) << 16);
        pk.y = f2bfbits(v0.z) | (f2bfbits(v0.w) << 16);
        pk.z = f2bfbits(v1.x) | (f2bfbits(v1.y) << 16);
        pk.w = f2bfbits(v1.z) | (f2bfbits(v1.w) << 16);
      }
      a[kc] = __builtin_bit_cast(bf16x8, pk);
    }
#pragma unroll
    for (int nc = 0; nc < 8; nc++) {
      f32x4 acc = {0.f, 0.f, 0.f, 0.f};
#pragma unroll
      for (int kc = 0; kc < 4; kc++) {
        uint4 bu = *(const uint4*)(Wt + (size_t)(nc * 16 + m) * F + kc * 32 + q * 8);
        acc = __builtin_amdgcn_mfma_f32_16x16x32_bf16(
            a[kc], __builtin_bit_cast(bf16x8, bu), acc, 0, 0, 0);
      }
#pragma unroll
      for (int r = 0; r < 4; r++) {
        int gr = m0 + q * 4 + r;
        if (gr < n)
          xwb[(size_t)gr * F + nc * 16 + m] = (unsigned short)f2bfbits(acc[r]);
      }
    }
  }
}

// ---- K1.5: pre-scale xw rows by their own dis = rsqrt(deg+1) --------------
// y[v] = dis[v] * xw[v], stored fp16 IN PLACE (finer quantum than bf16, so
// per-term rounding error does not grow vs the old f32-scale path).
// This deletes the per-neighbor scattered deg gather + rsqrt from K2.
__global__ __launch_bounds__(256) void scale_kernel(
    const int* __restrict__ deg, unsigned short* __restrict__ xwb, int n) {
  int i = blockIdx.x * 256 + threadIdx.x;  // one 16B chunk (8 elems) per thread
  if (i >= n * 16) return;
  int v = i >> 4;
  float dv = rsqrtf((float)(deg[(size_t)v * 16] + 1));
  uint4 u = ((uint4*)xwb)[i];
  unsigned int w[4] = {u.x, u.y, u.z, u.w};
#pragma unroll
  for (int k = 0; k < 4; k++) {
    float lo = __uint_as_float(w[k] << 16) * dv;          // bf16 -> f32, scale
    float hi = __uint_as_float(w[k] & 0xffff0000u) * dv;
    unsigned short hl = __half_as_ushort(__float2half_rn(lo));
    unsigned short hh = __half_as_ushort(__float2half_rn(hi));
    w[k] = (unsigned int)hl | ((unsigned int)hh << 16);
  }
  ((uint4*)xwb)[i] = make_uint4(w[0], w[1], w[2], w[3]);
}

// ---- K2: pull aggregation + bias + relu + classifier (fp16 gather) --------
// h[v] = dv * (y[v] + sum_{s in N(v)} y[s]); inner loop is a pure masked add.
__global__ __launch_bounds__(256) void agg_kernel(
    const int* __restrict__ deg, const unsigned short* __restrict__ bucket,
    const unsigned int* __restrict__ ywb, const int* __restrict__ ovf_cnt,
    const int* __restrict__ ovf, const float* __restrict__ gcn_bias,
    const float* __restrict__ Wc, const float* __restrict__ bc,
    float* __restrict__ out, int n) {
  int wave = threadIdx.x >> 6;
  int lane = threadIdx.x & 63;
  int v = blockIdx.x * 4 + wave;
  if (v >= n) return;
  int d = deg[(size_t)v * 16];
  float dv = rsqrtf((float)(d + 1));  // +1 self loop, always > 0
  float ax, ay;
  {
    unsigned int u = ywb[(size_t)v * 64 + lane];  // self loop: + y[v]
    ax = __half2float(__ushort_as_half((unsigned short)(u & 0xffffu)));
    ay = __half2float(__ushort_as_half((unsigned short)(u >> 16)));
  }
  int eend = d < CAP ? d : CAP;
  const unsigned short* bkt = bucket + (size_t)v * CAP;
  if (eend > 0) {
    // 16-wide clamped+predicated prologue: one 64B line read as 2 uint4,
    // all 16 gathers in flight before any FMA waits. Covers deg<=16 (~90%).
    uint4 b0 = *(const uint4*)(bkt);
    uint4 b1 = *(const uint4*)(bkt + 8);
    unsigned int wv[8] = {b0.x, b0.y, b0.z, b0.w, b1.x, b1.y, b1.z, b1.w};
    int s[16];
    unsigned int u[16];
#pragma unroll
    for (int q = 0; q < 16; q++) {
      int raw = (q & 1) ? (int)(wv[q >> 1] >> 16) : (int)(wv[q >> 1] & 0xffffu);
      s[q] = (q < eend) ? raw : 0;  // clamp padded slots to valid node 0
    }
#pragma unroll
    for (int q = 0; q < 16; q++) u[q] = ywb[(size_t)s[q] * 64 + lane];
#pragma unroll
    for (int q = 0; q < 16; q++) {
      float msk = (q < eend) ? 1.f : 0.f;
      ax = fmaf(msk, __half2float(__ushort_as_half((unsigned short)(u[q] & 0xffffu))), ax);
      ay = fmaf(msk, __half2float(__ushort_as_half((unsigned short)(u[q] >> 16))), ay);
    }
    // 8-wide clamped loop for deg > 16 (P ~ 10%)
    for (int j = 16; j < eend; j += 8) {
      int s2[8];
      unsigned int u2[8];
#pragma unroll
      for (int q = 0; q < 8; q++) s2[q] = bkt[j + q < eend ? j + q : 0];
#pragma unroll
      for (int q = 0; q < 8; q++) u2[q] = ywb[(size_t)s2[q] * 64 + lane];
#pragma unroll
      for (int q = 0; q < 8; q++) {
        float msk = (j + q < eend) ? 1.f : 0.f;
        ax = fmaf(msk, __half2float(__ushort_as_half((unsigned short)(u2[q] & 0xffffu))), ax);
        ay = fmaf(msk, __half2float(__ushort_as_half((unsigned short)(u2[q] >> 16))), ay);
      }
    }
  }
  if (d > CAP) {  // correctness fallback; statistically never taken
    int oc = *ovf_cnt;
    if (oc > OVF_MAX) oc = OVF_MAX;  // also guards poisoned-replay profiles
    for (int k = 0; k < oc; k++) {
      if (ovf[2 * k] == v) {
        int s3 = ovf[2 * k + 1];
        unsigned int uu = ywb[(size_t)s3 * 64 + lane];
        ax += __half2float(__ushort_as_half((unsigned short)(uu & 0xffffu)));
        ay += __half2float(__ushort_as_half((unsigned short)(uu >> 16)));
      }
    }
  }
  int f0 = lane * 2;
  float h0 = fmaxf(fmaf(dv, ax, gcn_bias[f0]), 0.f);
  float h1 = fmaxf(fmaf(dv, ay, gcn_bias[f0 + 1]), 0.f);
  float a0 = h0 * Wc[f0] + h1 * Wc[f0 + 1];
  float a1 = h0 * Wc[F + f0] + h1 * Wc[F + f0 + 1];
#pragma unroll
  for (int off = 32; off > 0; off >>= 1) {
    a0 += __shfl_down(a0, off);
    a1 += __shfl_down(a1, off);
  }
  if (lane == 0) {
    out[(size_t)v * 2 + 0] = a0 + bc[0];
    out[(size_t)v * 2 + 1] = a1 + bc[1];
  }
}

extern "C" void kernel_launch(void* const* d_in, const int* in_sizes, int n_in,
                              void* d_out, int out_size, void* d_ws, size_t ws_size,
                              hipStream_t stream) {
  const float* x        = (const float*)d_in[0];
  const float* W0       = (const float*)d_in[1];
  const float* w_ih     = (const float*)d_in[2];
  // d_in[3] = w_hh unused (h0 = 0)
  const float* b_ih     = (const float*)d_in[4];
  const float* b_hh     = (const float*)d_in[5];
  const float* gcn_bias = (const float*)d_in[6];
  const float* Wc       = (const float*)d_in[7];
  const float* bc       = (const float*)d_in[8];
  const int*   ei       = (const int*)d_in[9];

  const int n = in_sizes[0] / F;   // 50000
  const int e = in_sizes[9] / 2;   // 600000
  const int* row = ei;
  const int* col = ei + e;

  // workspace layout (256 B aligned chunks)
  char* wsb = (char*)d_ws;
  unsigned short* Wt = (unsigned short*)wsb;  wsb += 32768;        // bf16 W^T
  int*   deg     = (int*)wsb;                 wsb += (size_t)n * 64;  // 1 ctr / 64B line
  int*   ovf_cnt = (int*)wsb;                 wsb += 256;
  int*   ovf     = (int*)wsb;                 wsb += 8 * OVF_MAX;  // overflow pairs
  unsigned short* bucket = (unsigned short*)wsb;
  wsb += (size_t)n * CAP * 2;                                      // 3.2 MB, 64B/node
  unsigned short* xwb = (unsigned short*)wsb;                      // n*128, bf16 -> fp16

  const int NT = (n + 63) / 64;  // 782 xw tiles

  // K0: lstm (32 blocks) || zero padded deg + ovf_cnt (128 blocks)
  lstm_zero_kernel<<<32 + 128, 256, 0, stream>>>(W0, w_ih, b_ih, b_hh, Wt,
                                                 deg, ovf_cnt, n);

  // K1: XCD-local single-pass bucket fill (NF blocks) || xw = x@W MFMA (NT)
  fill_xw_kernel<<<NF + NT, 256, 0, stream>>>(row, col, deg, bucket, ovf_cnt,
                                              ovf, x, Wt, xwb, n, e);

  // K1.5: y = dis * xw (in place, fp16)
  scale_kernel<<<(n * 16 + 255) / 256, 256, 0, stream>>>(deg, xwb, n);

  // K2: fused pull-aggregation + bias + relu + classifier
  agg_kernel<<<(n + 3) / 4, 256, 0, stream>>>(deg, bucket,
                                              (const unsigned int*)xwb,
                                              ovf_cnt, ovf, gcn_bias, Wc, bc,
                                              (float*)d_out, n);
}